// Round 12
// baseline (253.439 us; speedup 1.0000x reference)
//
#include <hip/hip_runtime.h>

typedef unsigned short ushort_t;
typedef __attribute__((ext_vector_type(8))) short short8;
typedef __attribute__((ext_vector_type(4))) float f32x4;

#define MFMA_BF16(a, b, c) __builtin_amdgcn_mfma_f32_16x16x32_bf16((a), (b), (c), 0, 0, 0)

#define T_LEN 1024
#define BATCH 4
#define NHEAD 16
#define DHEAD 64
#define EMB 1024

__device__ __forceinline__ ushort_t f2bf(float f) {
  unsigned u = __float_as_uint(f);
  u += 0x7fffu + ((u >> 16) & 1u);
  return (ushort_t)(u >> 16);
}

// ---------------- elementwise ----------------
__global__ void sample_bf16_kernel(const float* __restrict__ mu, const float* __restrict__ rho,
                                   const float* __restrict__ eps, ushort_t* __restrict__ out, int n) {
  int i = blockIdx.x * 256 + threadIdx.x;
  if (i < n) {
    float sp = log1pf(__expf(rho[i]));
    out[i] = f2bf(mu[i] + sp * eps[i]);
  }
}

__global__ void sample_f32_kernel(const float* __restrict__ mu, const float* __restrict__ rho,
                                  const float* __restrict__ eps, float* __restrict__ out, int n) {
  int i = blockIdx.x * 256 + threadIdx.x;
  if (i < n) {
    float sp = log1pf(__expf(rho[i]));
    out[i] = mu[i] + sp * eps[i];
  }
}

__global__ void cast_bf16_kernel(const float* __restrict__ in, ushort_t* __restrict__ out, int n) {
  int i = blockIdx.x * 256 + threadIdx.x;
  if (i < n) out[i] = f2bf(in[i]);
}

// zero the rhp pad rows (phys rows 0..63 and 1088..1151 per head)
__global__ void zero_rhp_pad_kernel(ushort_t* __restrict__ rhp) {
  int idx = blockIdx.x * 256 + threadIdx.x;   // 16*128*64 = 131072
  int dd = idx & 63;
  int pr = (idx >> 6) & 127;
  int h = idx >> 13;
  int phys = (pr < 64) ? pr : (pr - 64 + 1088);
  rhp[((size_t)h * 1152 + phys) * 64 + dd] = 0;
}

// ---------------- GEMM: C[M][N] = A[M][K] * Bt[N][K]^T + bias[N] (f32 out) ----------------
__global__ __launch_bounds__(256, 2)
void gemm_bt_kernel(const ushort_t* __restrict__ A, const ushort_t* __restrict__ Bt,
                    const float* __restrict__ bias, float* __restrict__ C,
                    int M, int N, int K) {
  __shared__ ushort_t As[128 * 32];
  __shared__ ushort_t Bs[128 * 32];
  const int tid = threadIdx.x;
  const int w = tid >> 6, l = tid & 63;
  const int m0 = blockIdx.x * 128, n0 = blockIdx.y * 128;
  const int wr = w >> 1, wc = w & 1;
  const int fr = l & 15, fk = (l >> 4) * 8;

  f32x4 acc[4][4] = {};

  for (int k0 = 0; k0 < K; k0 += 32) {
    __syncthreads();
#pragma unroll
    for (int p = 0; p < 2; ++p) {
      int c = p * 256 + tid;
      int row = c >> 2, col = (c & 3) * 8;
      *(short8*)(&As[c * 8]) = *(const short8*)(&A[(size_t)(m0 + row) * K + k0 + col]);
      *(short8*)(&Bs[c * 8]) = *(const short8*)(&Bt[(size_t)(n0 + row) * K + k0 + col]);
    }
    __syncthreads();
    short8 af[4], bf[4];
#pragma unroll
    for (int mi = 0; mi < 4; ++mi) af[mi] = *(const short8*)(&As[(wr * 64 + mi * 16 + fr) * 32 + fk]);
#pragma unroll
    for (int ni = 0; ni < 4; ++ni) bf[ni] = *(const short8*)(&Bs[(wc * 64 + ni * 16 + fr) * 32 + fk]);
#pragma unroll
    for (int mi = 0; mi < 4; ++mi)
#pragma unroll
      for (int ni = 0; ni < 4; ++ni)
        acc[mi][ni] = MFMA_BF16(af[mi], bf[ni], acc[mi][ni]);
  }

#pragma unroll
  for (int ni = 0; ni < 4; ++ni) {
    int col = n0 + wc * 64 + ni * 16 + fr;
    float bv = bias[col];
#pragma unroll
    for (int mi = 0; mi < 4; ++mi) {
#pragma unroll
      for (int q = 0; q < 4; ++q) {
        int row = m0 + wr * 64 + mi * 16 + (l >> 4) * 4 + q;
        C[(size_t)row * N + col] = acc[mi][ni][q] + bv;
      }
    }
  }
}

// ---------------- fused QKV GEMM: epilogue writes qrw/qrr/kb/vt directly ----------------
__global__ __launch_bounds__(256, 2)
void gemm_qkv_fused_kernel(const ushort_t* __restrict__ A, const ushort_t* __restrict__ Bt,
                           const float* __restrict__ bias,
                           const float* __restrict__ rwb, const float* __restrict__ rrb,
                           ushort_t* __restrict__ qrw, ushort_t* __restrict__ qrr,
                           ushort_t* __restrict__ kbuf, ushort_t* __restrict__ vt) {
  __shared__ ushort_t As[128 * 32];
  __shared__ ushort_t Bs[128 * 32];
  const int K = 1024;
  const int tid = threadIdx.x;
  const int w = tid >> 6, l = tid & 63;
  const int m0 = blockIdx.x * 128, n0 = blockIdx.y * 128;
  const int wr = w >> 1, wc = w & 1;
  const int fr = l & 15, fk = (l >> 4) * 8;

  f32x4 acc[4][4] = {};

  for (int k0 = 0; k0 < K; k0 += 32) {
    __syncthreads();
#pragma unroll
    for (int p = 0; p < 2; ++p) {
      int c = p * 256 + tid;
      int row = c >> 2, col = (c & 3) * 8;
      *(short8*)(&As[c * 8]) = *(const short8*)(&A[(size_t)(m0 + row) * K + k0 + col]);
      *(short8*)(&Bs[c * 8]) = *(const short8*)(&Bt[(size_t)(n0 + row) * K + k0 + col]);
    }
    __syncthreads();
    short8 af[4], bf[4];
#pragma unroll
    for (int mi = 0; mi < 4; ++mi) af[mi] = *(const short8*)(&As[(wr * 64 + mi * 16 + fr) * 32 + fk]);
#pragma unroll
    for (int ni = 0; ni < 4; ++ni) bf[ni] = *(const short8*)(&Bs[(wc * 64 + ni * 16 + fr) * 32 + fk]);
#pragma unroll
    for (int mi = 0; mi < 4; ++mi)
#pragma unroll
      for (int ni = 0; ni < 4; ++ni)
        acc[mi][ni] = MFMA_BF16(af[mi], bf[ni], acc[mi][ni]);
  }

#pragma unroll
  for (int ni = 0; ni < 4; ++ni) {
    int col = n0 + wc * 64 + ni * 16 + fr;
    int part = col >> 10;
    int e = col & 1023;
    int hh = e >> 6, dd = e & 63;
    float bv = bias[col];
    float rwv = rwb[e];
    float rrv = rrb[e];
#pragma unroll
    for (int mi = 0; mi < 4; ++mi) {
#pragma unroll
      for (int q = 0; q < 4; ++q) {
        int row = m0 + wr * 64 + mi * 16 + (l >> 4) * 4 + q;
        int t = row >> 2, b = row & 3;
        float v = acc[mi][ni][q] + bv;
        if (part == 0) {
          unsigned idx = (((unsigned)(b * 16 + hh) * 1024 + t) << 6) + dd;
          qrw[idx] = f2bf(v + rwv);
          qrr[idx] = f2bf(v + rrv);
        } else if (part == 1) {
          unsigned idx = (((unsigned)(b * 16 + hh) * 1024 + t) << 6) + dd;
          kbuf[idx] = f2bf(v);
        } else {
          vt[(((unsigned)(b * 16 + hh) * 64 + dd) << 10) + t] = f2bf(v);
        }
      }
    }
  }
}

// ---------------- fused pos GEMM: epilogue writes rhp[h][64+t][dd] directly ----------------
__global__ __launch_bounds__(256, 2)
void gemm_pos_fused_kernel(const ushort_t* __restrict__ A, const ushort_t* __restrict__ Bt,
                           const float* __restrict__ bias, ushort_t* __restrict__ rhp) {
  __shared__ ushort_t As[128 * 32];
  __shared__ ushort_t Bs[128 * 32];
  const int K = 1024;
  const int tid = threadIdx.x;
  const int w = tid >> 6, l = tid & 63;
  const int m0 = blockIdx.x * 128, n0 = blockIdx.y * 128;
  const int wr = w >> 1, wc = w & 1;
  const int fr = l & 15, fk = (l >> 4) * 8;

  f32x4 acc[4][4] = {};

  for (int k0 = 0; k0 < K; k0 += 32) {
    __syncthreads();
#pragma unroll
    for (int p = 0; p < 2; ++p) {
      int c = p * 256 + tid;
      int row = c >> 2, col = (c & 3) * 8;
      *(short8*)(&As[c * 8]) = *(const short8*)(&A[(size_t)(m0 + row) * K + k0 + col]);
      *(short8*)(&Bs[c * 8]) = *(const short8*)(&Bt[(size_t)(n0 + row) * K + k0 + col]);
    }
    __syncthreads();
    short8 af[4], bf[4];
#pragma unroll
    for (int mi = 0; mi < 4; ++mi) af[mi] = *(const short8*)(&As[(wr * 64 + mi * 16 + fr) * 32 + fk]);
#pragma unroll
    for (int ni = 0; ni < 4; ++ni) bf[ni] = *(const short8*)(&Bs[(wc * 64 + ni * 16 + fr) * 32 + fk]);
#pragma unroll
    for (int mi = 0; mi < 4; ++mi)
#pragma unroll
      for (int ni = 0; ni < 4; ++ni)
        acc[mi][ni] = MFMA_BF16(af[mi], bf[ni], acc[mi][ni]);
  }

#pragma unroll
  for (int ni = 0; ni < 4; ++ni) {
    int col = n0 + wc * 64 + ni * 16 + fr;
    int hh = col >> 6, dd = col & 63;
    float bv = bias[col];
#pragma unroll
    for (int mi = 0; mi < 4; ++mi) {
#pragma unroll
      for (int q = 0; q < 4; ++q) {
        int t = m0 + wr * 64 + mi * 16 + (l >> 4) * 4 + q;
        rhp[((unsigned)hh * 1152 + 64 + t) * 64 + dd] = f2bf(acc[mi][ni][q] + bv);
      }
    }
  }
}

// ---------------- fused rel-shift attention v6: LDS staging + split-j ----------------
// v5 body (LDS K/V staging, static-max softmax) + split-j: each (bh,strip) pair is handled
// by TWO blocks over disjoint j-ranges. Static-max makes partials exactly additive:
// o_tot = oA+oB, s_tot = sA+sB (exp(-20) reference is global, no max rescale). Blocks write
// unnormalized (o,s) partials; a bandwidth-bound combine kernel divides. 2048 blocks ->
// 2x resident waves. bid mapping split-major: inner = bid&1023 keeps XCD head-pair locality.
__global__ __launch_bounds__(256, 2)
void attn_kernel(const ushort_t* __restrict__ qrw, const ushort_t* __restrict__ qrr,
                 const ushort_t* __restrict__ kb, const ushort_t* __restrict__ vt,
                 const ushort_t* __restrict__ rhp,
                 float* __restrict__ po, float* __restrict__ ps) {
  __shared__ __attribute__((aligned(16))) ushort_t KV[2][8192];  // [buf][K 8KB | V 8KB]
  __shared__ __attribute__((aligned(16))) char PtB[4][2048];     // per-wave P transpose

  const int tid = threadIdx.x, w = tid >> 6, l = tid & 63;
  const int bid = blockIdx.x;
  const int split = bid >> 10;                     // 0: first half of j, 1: second half
  const int inner = bid & 1023;
  const int g = inner & 63;
  const int h = ((g & 7) << 1) | ((g >> 3) & 1);   // inner%8 fixes the head-pair (XCD L2 locality)
  const int b = g >> 4;
  const int bh = b * 16 + h;
  const int sx = 15 - (inner >> 6);                // reversed: big strips first
  const int istrip = sx * 64 + w * 16;             // this wave's 16 q-rows
  const int fr = l & 15, fkq = (l >> 4) * 8;
  const float scale = 0.125f;
  char* Pw = PtB[w];

  const int njt_full = sx + 1;                     // uniform across the block's 4 waves
  const int nA = (njt_full + 1) >> 1;
  const int jbeg = split ? nA : 0;
  const int jend = split ? njt_full : nA;

  // Q fragments in registers for the whole loop
  short8 aqw0, aqw1, aqr0, aqr1;
  {
    unsigned qb = ((unsigned)bh * T_LEN + istrip + fr) * 64 + fkq;
    aqw0 = *(const short8*)(qrw + qb);
    aqw1 = *(const short8*)(qrw + qb + 32);
    aqr0 = *(const short8*)(qrr + qb);
    aqr1 = *(const short8*)(qrr + qb + 32);
  }

  // staging geometry: wave w stages K rows [16w..16w+15] and V d-rows [16w..16w+15]
  const int srow = 16 * w + (l >> 3);                          // +8 for second load
  const unsigned sswz = (unsigned)(((l & 7) ^ (l >> 3)) << 4); // write-side swizzle (bytes)
  const unsigned kgcol = (unsigned)(l & 7) * 8;                // global col (elems)
  const unsigned swzr = (unsigned)(fr & 7) << 4;               // read-side swizzle (bytes)

  const unsigned rbase = ((unsigned)h * 1152 + 64 + 1008 - istrip + fr) * 64 + fkq;

  float s_run[4] = {0.f, 0.f, 0.f, 0.f};
  f32x4 o[4] = {};                                 // [d-group][q]

  short8 sg0, sg1, sg2, sg3;                       // staged K(2) + V(2) in-flight regs
#define STAGE_LOAD(J0)                                                              \
  do {                                                                              \
    sg0 = *(const short8*)(kb + ((unsigned)bh * 1024 + (unsigned)(J0) + srow) * 64 + kgcol);      \
    sg1 = *(const short8*)(kb + ((unsigned)bh * 1024 + (unsigned)(J0) + srow + 8) * 64 + kgcol);  \
    sg2 = *(const short8*)(vt + ((unsigned)bh * 64 + srow) * 1024 + (unsigned)(J0) + kgcol);      \
    sg3 = *(const short8*)(vt + ((unsigned)bh * 64 + srow + 8) * 1024 + (unsigned)(J0) + kgcol);  \
  } while (0)
#define STAGE_WRITE(BUF)                                                            \
  do {                                                                              \
    char* KS_ = (char*)KV[BUF];                                                     \
    *(short8*)(KS_ + (unsigned)srow * 128 + sswz) = sg0;                            \
    *(short8*)(KS_ + (unsigned)(srow + 8) * 128 + sswz) = sg1;                      \
    *(short8*)(KS_ + 8192 + (unsigned)srow * 128 + sswz) = sg2;                     \
    *(short8*)(KS_ + 8192 + (unsigned)(srow + 8) * 128 + sswz) = sg3;               \
  } while (0)

  // prologue: stage first tile of this split's range
  if (jbeg < jend) {
    STAGE_LOAD(jbeg << 6);
    STAGE_WRITE(jbeg & 1);
  }
  __syncthreads();

  for (int jt = jbeg; jt < jend; ++jt) {
    const int j0 = jt << 6;
    const char* KS = (const char*)KV[jt & 1];

    // ---- issue next tile's stage loads early (latency hides under this tile) ----
    if (jt + 1 < jend) STAGE_LOAD((jt + 1) << 6);

    // ---- R loads (global -> regs, per-wave band) ----
    short8 rf[10];
    {
      unsigned roff = rbase + (unsigned)j0 * 64;
#pragma unroll
      for (int f = 0; f < 5; ++f) {
        rf[2 * f] = *(const short8*)(rhp + roff + f * 1024);
        rf[2 * f + 1] = *(const short8*)(rhp + roff + f * 1024 + 32);
      }
    }

    // ---- K from LDS (swizzled), AC / BD MFMA ----
    f32x4 ac[4] = {};
    f32x4 pb[5] = {};
    {
      short8 kf[8];
#pragma unroll
      for (int f = 0; f < 4; ++f) {
        unsigned rowb = (unsigned)(f * 16 + fr) * 128;
        kf[2 * f] = *(const short8*)(KS + rowb + (((unsigned)fkq * 2) ^ swzr));
        kf[2 * f + 1] = *(const short8*)(KS + rowb + (((unsigned)fkq * 2 + 64) ^ swzr));
      }
      __builtin_amdgcn_s_setprio(1);
#pragma unroll
      for (int f = 0; f < 4; ++f) {
        ac[f] = MFMA_BF16(aqw0, kf[2 * f], ac[f]);
        ac[f] = MFMA_BF16(aqw1, kf[2 * f + 1], ac[f]);
      }
#pragma unroll
      for (int f = 0; f < 5; ++f) {
        pb[f] = MFMA_BF16(aqr0, rf[2 * f], pb[f]);
        pb[f] = MFMA_BF16(aqr1, rf[2 * f + 1], pb[f]);
      }
      __builtin_amdgcn_s_setprio(0);
    }

    // ---- V from LDS (swizzled) -- issue before softmax so lgkm overlaps ----
    short8 vf[8];
#pragma unroll
    for (int dg = 0; dg < 4; ++dg) {
      unsigned rowb = 8192 + (unsigned)(dg * 16 + fr) * 128;
      vf[2 * dg] = *(const short8*)(KS + rowb + (((unsigned)fkq * 2) ^ swzr));
      vf[2 * dg + 1] = *(const short8*)(KS + rowb + (((unsigned)(64 + fkq * 2)) ^ swzr));
    }

    // ---- rel-shift gather + static-max softmax: P straight to LDS ----
#pragma unroll
    for (int q = 0; q < 4; ++q) {
      int ri = 4 * (l >> 4) + q;
      int e = 15 + fr - ri;                   // in [0,30]
      int src = (l & 48) | (e & 15);
      float sh[5];
#pragma unroll
      for (int f = 0; f < 5; ++f) sh[f] = __shfl(pb[f][q], src, 64);
      int hi = e >> 4;
      int ig = istrip + ri;
#pragma unroll
      for (int ni = 0; ni < 4; ++ni) {
        float pv = hi ? sh[ni + 1] : sh[ni];
        float s = (ac[ni][q] + pv) * scale - 20.0f;
        int jg = j0 + ni * 16 + fr;
        float p = (jg > ig) ? 0.f : __expf(s);
        *(ushort_t*)(Pw + (((ri * 128) + (ni * 16 + fr) * 2) ^ ((ri & 7) << 4))) = f2bf(p);
        s_run[q] += p;
      }
    }

    // ---- PV ----
    {
      short8 pa0 = *(const short8*)(Pw + ((fr * 128 + fkq * 2) ^ ((fr & 7) << 4)));
      short8 pa1 = *(const short8*)(Pw + ((fr * 128 + 64 + fkq * 2) ^ ((fr & 7) << 4)));
      __builtin_amdgcn_s_setprio(1);
#pragma unroll
      for (int dg = 0; dg < 4; ++dg) {
        o[dg] = MFMA_BF16(pa0, vf[2 * dg], o[dg]);
        o[dg] = MFMA_BF16(pa1, vf[2 * dg + 1], o[dg]);
      }
      __builtin_amdgcn_s_setprio(0);
    }

    // ---- write staged regs into the other buffer, then sync ----
    if (jt + 1 < jend) STAGE_WRITE((jt + 1) & 1);
    __syncthreads();
  }

  // ---- epilogue: row-sum reduce, write UNNORMALIZED partials (o, s) ----
#pragma unroll
  for (int q = 0; q < 4; ++q) {
    float sq = s_run[q];
#pragma unroll
    for (int o2 = 8; o2; o2 >>= 1) sq += __shfl_xor(sq, o2, 64);
    s_run[q] = sq;
  }
#pragma unroll
  for (int q = 0; q < 4; ++q) {
    int ig = istrip + 4 * (l >> 4) + q;
    if (fr == 0) ps[((unsigned)split * 64 + bh) * 1024 + ig] = s_run[q];
#pragma unroll
    for (int dg = 0; dg < 4; ++dg) {
      int dd = dg * 16 + fr;
      po[(((unsigned)split * 64 + bh) * 1024 + ig) * 64 + dd] = o[dg][q];
    }
  }
}

// ---------------- combine: ctx = (oA+oB)/(sA+sB), layout [T][B][E] bf16 ----------------
__global__ void attn_combine_kernel(const float* __restrict__ po, const float* __restrict__ ps,
                                    ushort_t* __restrict__ ctx) {
  int idx = blockIdx.x * 256 + threadIdx.x;        // [bh][t][dd], 64*1024*64
  int dd = idx & 63;
  int t = (idx >> 6) & 1023;
  int bh = idx >> 16;
  int b = bh >> 4, h = bh & 15;
  float ov = po[idx] + po[idx + 4194304];
  float sv = ps[bh * 1024 + t] + ps[bh * 1024 + t + 65536];
  ctx[((size_t)t * BATCH + b) * EMB + h * 64 + dd] = f2bf(ov / sv);
}

// ---------------- launch ----------------
extern "C" void kernel_launch(void* const* d_in, const int* in_sizes, int n_in,
                              void* d_out, int out_size, void* d_ws, size_t ws_size,
                              hipStream_t stream) {
  (void)in_sizes; (void)n_in; (void)out_size; (void)ws_size;
  const float* x = (const float*)d_in[0];
  const float* pos = (const float*)d_in[1];
  const float* in_w_mu = (const float*)d_in[3];
  const float* in_w_rho = (const float*)d_in[4];
  const float* in_w_eps = (const float*)d_in[5];
  const float* in_b_mu = (const float*)d_in[6];
  const float* in_b_rho = (const float*)d_in[7];
  const float* in_b_eps = (const float*)d_in[8];
  const float* pos_w_mu = (const float*)d_in[9];
  const float* pos_w_rho = (const float*)d_in[10];
  const float* pos_w_eps = (const float*)d_in[11];
  const float* pos_b_mu = (const float*)d_in[12];
  const float* pos_b_rho = (const float*)d_in[13];
  const float* pos_b_eps = (const float*)d_in[14];
  const float* out_w_mu = (const float*)d_in[15];
  const float* out_w_rho = (const float*)d_in[16];
  const float* out_w_eps = (const float*)d_in[17];
  const float* out_b_mu = (const float*)d_in[18];
  const float* out_b_rho = (const float*)d_in[19];
  const float* out_b_eps = (const float*)d_in[20];
  const float* rw_mu = (const float*)d_in[21];
  const float* rw_rho = (const float*)d_in[22];
  const float* rw_eps = (const float*)d_in[23];
  const float* rr_mu = (const float*)d_in[24];
  const float* rr_rho = (const float*)d_in[25];
  const float* rr_eps = (const float*)d_in[26];

  char* ws = (char*)d_ws;
  ushort_t* in_w_bf  = (ushort_t*)(ws + 0);          // 3072x1024 bf16
  ushort_t* pos_w_bf = (ushort_t*)(ws + 6291456);    // 1024x1024 bf16
  ushort_t* out_w_bf = (ushort_t*)(ws + 8388608);    // 1024x1024 bf16
  float* in_b  = (float*)(ws + 10485760);            // 3072
  float* pos_b = (float*)(ws + 10498048);            // 1024
  float* out_b = (float*)(ws + 10502144);            // 1024
  float* rwb   = (float*)(ws + 10506240);            // 1024
  float* rrb   = (float*)(ws + 10510336);            // 1024
  ushort_t* x_bf    = (ushort_t*)(ws + 10514432);    // 4096x1024 bf16
  ushort_t* posx_bf = (ushort_t*)(ws + 18903040);    // 1024x1024 bf16
  ushort_t* qrw = (ushort_t*)(ws + 21000192);        // [B][H][T][64] bf16
  ushort_t* qrr = (ushort_t*)(ws + 29388800);
  ushort_t* kb  = (ushort_t*)(ws + 37777408);
  ushort_t* vt  = (ushort_t*)(ws + 46166016);        // [B][H][64][T] bf16
  ushort_t* rhp = (ushort_t*)(ws + 54554624);        // [H][1152][64] bf16
  float* po = (float*)(ws + 56913920);               // [2][64][1024][64] f32 (33.5 MB)
  float* ps = (float*)(ws + 90468352);               // [2][64][1024] f32 (512 KB)
  ushort_t* ctx = (ushort_t*)(ws + 90992640);        // [T][B][E] bf16

  sample_bf16_kernel<<<12288, 256, 0, stream>>>(in_w_mu, in_w_rho, in_w_eps, in_w_bf, 3145728);
  sample_bf16_kernel<<<4096, 256, 0, stream>>>(pos_w_mu, pos_w_rho, pos_w_eps, pos_w_bf, 1048576);
  sample_bf16_kernel<<<4096, 256, 0, stream>>>(out_w_mu, out_w_rho, out_w_eps, out_w_bf, 1048576);
  sample_f32_kernel<<<12, 256, 0, stream>>>(in_b_mu, in_b_rho, in_b_eps, in_b, 3072);
  sample_f32_kernel<<<4, 256, 0, stream>>>(pos_b_mu, pos_b_rho, pos_b_eps, pos_b, 1024);
  sample_f32_kernel<<<4, 256, 0, stream>>>(out_b_mu, out_b_rho, out_b_eps, out_b, 1024);
  sample_f32_kernel<<<4, 256, 0, stream>>>(rw_mu, rw_rho, rw_eps, rwb, 1024);
  sample_f32_kernel<<<4, 256, 0, stream>>>(rr_mu, rr_rho, rr_eps, rrb, 1024);
  cast_bf16_kernel<<<16384, 256, 0, stream>>>(x, x_bf, 4194304);
  cast_bf16_kernel<<<4096, 256, 0, stream>>>(pos, posx_bf, 1048576);
  zero_rhp_pad_kernel<<<512, 256, 0, stream>>>(rhp);

  gemm_qkv_fused_kernel<<<dim3(32, 24), 256, 0, stream>>>(x_bf, in_w_bf, in_b, rwb, rrb,
                                                          qrw, qrr, kb, vt);
  gemm_pos_fused_kernel<<<dim3(8, 8), 256, 0, stream>>>(posx_bf, pos_w_bf, pos_b, rhp);

  attn_kernel<<<dim3(2048), 256, 0, stream>>>(qrw, qrr, kb, vt, rhp, po, ps);
  attn_combine_kernel<<<16384, 256, 0, stream>>>(po, ps, ctx);

  gemm_bt_kernel<<<dim3(32, 8), 256, 0, stream>>>(ctx, out_w_bf, out_b, (float*)d_out, 4096, 1024, 1024);
}

// Round 13
// 223.888 us; speedup vs baseline: 1.1320x; 1.1320x over previous
//
#include <hip/hip_runtime.h>

typedef unsigned short ushort_t;
typedef __attribute__((ext_vector_type(8))) short short8;
typedef __attribute__((ext_vector_type(4))) float f32x4;
typedef __attribute__((ext_vector_type(4))) unsigned short ush4;

#define MFMA_BF16(a, b, c) __builtin_amdgcn_mfma_f32_16x16x32_bf16((a), (b), (c), 0, 0, 0)

// async global->LDS, 16B/lane; LDS dest is wave-uniform base + lane*16 (linear layout required)
#define GLOAD_LDS16(GP, LP)                                                       \
  __builtin_amdgcn_global_load_lds(                                               \
      (const __attribute__((address_space(1))) void*)(GP),                        \
      (__attribute__((address_space(3))) void*)(LP), 16, 0, 0)

#define T_LEN 1024
#define BATCH 4
#define NHEAD 16
#define DHEAD 64
#define EMB 1024

__device__ __forceinline__ ushort_t f2bf(float f) {
  unsigned u = __float_as_uint(f);
  u += 0x7fffu + ((u >> 16) & 1u);
  return (ushort_t)(u >> 16);
}

// ---------------- elementwise (vectorized x4) ----------------
__global__ void sample_bf16x4_kernel(const float* __restrict__ mu, const float* __restrict__ rho,
                                     const float* __restrict__ eps, ushort_t* __restrict__ out, int n4) {
  int i = blockIdx.x * 256 + threadIdx.x;
  if (i < n4) {
    f32x4 m = *(const f32x4*)(mu + i * 4);
    f32x4 r = *(const f32x4*)(rho + i * 4);
    f32x4 e = *(const f32x4*)(eps + i * 4);
    ush4 o;
#pragma unroll
    for (int j = 0; j < 4; ++j) o[j] = f2bf(m[j] + log1pf(__expf(r[j])) * e[j]);
    *(ush4*)(out + i * 4) = o;
  }
}

// all five bias vectors in one launch: 3072 + 4*1024 = 7168 threads
__global__ void sample_bias_kernel(
    const float* __restrict__ am, const float* __restrict__ ar, const float* __restrict__ ae, float* __restrict__ ao,
    const float* __restrict__ bm, const float* __restrict__ br, const float* __restrict__ be, float* __restrict__ bo,
    const float* __restrict__ cm, const float* __restrict__ cr, const float* __restrict__ ce, float* __restrict__ co,
    const float* __restrict__ dm, const float* __restrict__ dr, const float* __restrict__ de, float* __restrict__ dof,
    const float* __restrict__ em, const float* __restrict__ er, const float* __restrict__ ee, float* __restrict__ eo) {
  int i = blockIdx.x * 256 + threadIdx.x;
  if (i < 3072) {
    ao[i] = am[i] + log1pf(__expf(ar[i])) * ae[i];
  } else if (i < 4096) {
    int j = i - 3072; bo[j] = bm[j] + log1pf(__expf(br[j])) * be[j];
  } else if (i < 5120) {
    int j = i - 4096; co[j] = cm[j] + log1pf(__expf(cr[j])) * ce[j];
  } else if (i < 6144) {
    int j = i - 5120; dof[j] = dm[j] + log1pf(__expf(dr[j])) * de[j];
  } else if (i < 7168) {
    int j = i - 6144; eo[j] = em[j] + log1pf(__expf(er[j])) * ee[j];
  }
}

__global__ void cast_bf16x4_kernel(const float* __restrict__ in, ushort_t* __restrict__ out, int n4) {
  int i = blockIdx.x * 256 + threadIdx.x;
  if (i < n4) {
    f32x4 v = *(const f32x4*)(in + i * 4);
    ush4 o;
#pragma unroll
    for (int j = 0; j < 4; ++j) o[j] = f2bf(v[j]);
    *(ush4*)(out + i * 4) = o;
  }
}

// zero the rhp pad rows (phys rows 0..63 and 1088..1151 per head)
__global__ void zero_rhp_pad_kernel(ushort_t* __restrict__ rhp) {
  int idx = blockIdx.x * 256 + threadIdx.x;   // 16*128*64 = 131072
  int dd = idx & 63;
  int pr = (idx >> 6) & 127;
  int h = idx >> 13;
  int phys = (pr < 64) ? pr : (pr - 64 + 1088);
  rhp[((size_t)h * 1152 + phys) * 64 + dd] = 0;
}

// ---------------- GEMM: C[M][N] = A[M][K] * Bt[N][K]^T + bias[N] (f32 out) ----------------
// staging via global_load_lds width=16 (m97 pattern): LDS chunk c is linear in tid -> the
// wave-uniform-base + lane*16 dest requirement holds; __syncthreads drains vmcnt.
__global__ __launch_bounds__(256, 2)
void gemm_bt_kernel(const ushort_t* __restrict__ A, const ushort_t* __restrict__ Bt,
                    const float* __restrict__ bias, float* __restrict__ C,
                    int M, int N, int K) {
  __shared__ ushort_t As[128 * 32];
  __shared__ ushort_t Bs[128 * 32];
  const int tid = threadIdx.x;
  const int w = tid >> 6, l = tid & 63;
  const int m0 = blockIdx.x * 128, n0 = blockIdx.y * 128;
  const int wr = w >> 1, wc = w & 1;
  const int fr = l & 15, fk = (l >> 4) * 8;

  f32x4 acc[4][4] = {};

  for (int k0 = 0; k0 < K; k0 += 32) {
    __syncthreads();
#pragma unroll
    for (int p = 0; p < 2; ++p) {
      int c = p * 256 + tid;
      int row = c >> 2, col = (c & 3) * 8;
      GLOAD_LDS16(&A[(size_t)(m0 + row) * K + k0 + col], &As[c * 8]);
      GLOAD_LDS16(&Bt[(size_t)(n0 + row) * K + k0 + col], &Bs[c * 8]);
    }
    __syncthreads();
    short8 af[4], bf[4];
#pragma unroll
    for (int mi = 0; mi < 4; ++mi) af[mi] = *(const short8*)(&As[(wr * 64 + mi * 16 + fr) * 32 + fk]);
#pragma unroll
    for (int ni = 0; ni < 4; ++ni) bf[ni] = *(const short8*)(&Bs[(wc * 64 + ni * 16 + fr) * 32 + fk]);
#pragma unroll
    for (int mi = 0; mi < 4; ++mi)
#pragma unroll
      for (int ni = 0; ni < 4; ++ni)
        acc[mi][ni] = MFMA_BF16(af[mi], bf[ni], acc[mi][ni]);
  }

#pragma unroll
  for (int ni = 0; ni < 4; ++ni) {
    int col = n0 + wc * 64 + ni * 16 + fr;
    float bv = bias[col];
#pragma unroll
    for (int mi = 0; mi < 4; ++mi) {
#pragma unroll
      for (int q = 0; q < 4; ++q) {
        int row = m0 + wr * 64 + mi * 16 + (l >> 4) * 4 + q;
        C[(size_t)row * N + col] = acc[mi][ni][q] + bv;
      }
    }
  }
}

// ---------------- fused QKV GEMM: epilogue writes qrw/qrr/kb/vt directly ----------------
__global__ __launch_bounds__(256, 2)
void gemm_qkv_fused_kernel(const ushort_t* __restrict__ A, const ushort_t* __restrict__ Bt,
                           const float* __restrict__ bias,
                           const float* __restrict__ rwb, const float* __restrict__ rrb,
                           ushort_t* __restrict__ qrw, ushort_t* __restrict__ qrr,
                           ushort_t* __restrict__ kbuf, ushort_t* __restrict__ vt) {
  __shared__ ushort_t As[128 * 32];
  __shared__ ushort_t Bs[128 * 32];
  const int K = 1024;
  const int tid = threadIdx.x;
  const int w = tid >> 6, l = tid & 63;
  const int m0 = blockIdx.x * 128, n0 = blockIdx.y * 128;
  const int wr = w >> 1, wc = w & 1;
  const int fr = l & 15, fk = (l >> 4) * 8;

  f32x4 acc[4][4] = {};

  for (int k0 = 0; k0 < K; k0 += 32) {
    __syncthreads();
#pragma unroll
    for (int p = 0; p < 2; ++p) {
      int c = p * 256 + tid;
      int row = c >> 2, col = (c & 3) * 8;
      GLOAD_LDS16(&A[(size_t)(m0 + row) * K + k0 + col], &As[c * 8]);
      GLOAD_LDS16(&Bt[(size_t)(n0 + row) * K + k0 + col], &Bs[c * 8]);
    }
    __syncthreads();
    short8 af[4], bf[4];
#pragma unroll
    for (int mi = 0; mi < 4; ++mi) af[mi] = *(const short8*)(&As[(wr * 64 + mi * 16 + fr) * 32 + fk]);
#pragma unroll
    for (int ni = 0; ni < 4; ++ni) bf[ni] = *(const short8*)(&Bs[(wc * 64 + ni * 16 + fr) * 32 + fk]);
#pragma unroll
    for (int mi = 0; mi < 4; ++mi)
#pragma unroll
      for (int ni = 0; ni < 4; ++ni)
        acc[mi][ni] = MFMA_BF16(af[mi], bf[ni], acc[mi][ni]);
  }

#pragma unroll
  for (int ni = 0; ni < 4; ++ni) {
    int col = n0 + wc * 64 + ni * 16 + fr;
    int part = col >> 10;
    int e = col & 1023;
    int hh = e >> 6, dd = e & 63;
    float bv = bias[col];
    float rwv = rwb[e];
    float rrv = rrb[e];
#pragma unroll
    for (int mi = 0; mi < 4; ++mi) {
#pragma unroll
      for (int q = 0; q < 4; ++q) {
        int row = m0 + wr * 64 + mi * 16 + (l >> 4) * 4 + q;
        int t = row >> 2, b = row & 3;
        float v = acc[mi][ni][q] + bv;
        if (part == 0) {
          unsigned idx = (((unsigned)(b * 16 + hh) * 1024 + t) << 6) + dd;
          qrw[idx] = f2bf(v + rwv);
          qrr[idx] = f2bf(v + rrv);
        } else if (part == 1) {
          unsigned idx = (((unsigned)(b * 16 + hh) * 1024 + t) << 6) + dd;
          kbuf[idx] = f2bf(v);
        } else {
          vt[(((unsigned)(b * 16 + hh) * 64 + dd) << 10) + t] = f2bf(v);
        }
      }
    }
  }
}

// ---------------- fused pos GEMM: epilogue writes rhp[h][64+t][dd] directly ----------------
__global__ __launch_bounds__(256, 2)
void gemm_pos_fused_kernel(const ushort_t* __restrict__ A, const ushort_t* __restrict__ Bt,
                           const float* __restrict__ bias, ushort_t* __restrict__ rhp) {
  __shared__ ushort_t As[128 * 32];
  __shared__ ushort_t Bs[128 * 32];
  const int K = 1024;
  const int tid = threadIdx.x;
  const int w = tid >> 6, l = tid & 63;
  const int m0 = blockIdx.x * 128, n0 = blockIdx.y * 128;
  const int wr = w >> 1, wc = w & 1;
  const int fr = l & 15, fk = (l >> 4) * 8;

  f32x4 acc[4][4] = {};

  for (int k0 = 0; k0 < K; k0 += 32) {
    __syncthreads();
#pragma unroll
    for (int p = 0; p < 2; ++p) {
      int c = p * 256 + tid;
      int row = c >> 2, col = (c & 3) * 8;
      GLOAD_LDS16(&A[(size_t)(m0 + row) * K + k0 + col], &As[c * 8]);
      GLOAD_LDS16(&Bt[(size_t)(n0 + row) * K + k0 + col], &Bs[c * 8]);
    }
    __syncthreads();
    short8 af[4], bf[4];
#pragma unroll
    for (int mi = 0; mi < 4; ++mi) af[mi] = *(const short8*)(&As[(wr * 64 + mi * 16 + fr) * 32 + fk]);
#pragma unroll
    for (int ni = 0; ni < 4; ++ni) bf[ni] = *(const short8*)(&Bs[(wc * 64 + ni * 16 + fr) * 32 + fk]);
#pragma unroll
    for (int mi = 0; mi < 4; ++mi)
#pragma unroll
      for (int ni = 0; ni < 4; ++ni)
        acc[mi][ni] = MFMA_BF16(af[mi], bf[ni], acc[mi][ni]);
  }

#pragma unroll
  for (int ni = 0; ni < 4; ++ni) {
    int col = n0 + wc * 64 + ni * 16 + fr;
    int hh = col >> 6, dd = col & 63;
    float bv = bias[col];
#pragma unroll
    for (int mi = 0; mi < 4; ++mi) {
#pragma unroll
      for (int q = 0; q < 4; ++q) {
        int t = m0 + wr * 64 + mi * 16 + (l >> 4) * 4 + q;
        rhp[((unsigned)hh * 1152 + 64 + t) * 64 + dd] = f2bf(acc[mi][ni][q] + bv);
      }
    }
  }
}

// ---------------- fused rel-shift attention v5 (R11, reverted from split-j) ----------------
// LDS K/V staging (reg-staged, double-buffered, XOR-swizzled), static-max softmax,
// per-wave causal bound, setprio around MFMA clusters. Split-j removed: residency is capped
// at 3 blocks/CU by unified regs, so 2x grid only added partial-write traffic (R12: +5us).
__global__ __launch_bounds__(256, 2)
void attn_kernel(const ushort_t* __restrict__ qrw, const ushort_t* __restrict__ qrr,
                 const ushort_t* __restrict__ kb, const ushort_t* __restrict__ vt,
                 const ushort_t* __restrict__ rhp, ushort_t* __restrict__ ctx) {
  __shared__ __attribute__((aligned(16))) ushort_t KV[2][8192];  // [buf][K 8KB | V 8KB]
  __shared__ __attribute__((aligned(16))) char PtB[4][2048];     // per-wave P transpose

  const int tid = threadIdx.x, w = tid >> 6, l = tid & 63;
  const int bid = blockIdx.x;
  const int g = bid & 63;
  const int h = ((g & 7) << 1) | ((g >> 3) & 1);   // bid%8 fixes the head-pair (XCD L2 locality)
  const int b = g >> 4;
  const int bh = b * 16 + h;
  const int sx = 15 - (bid >> 6);                  // reversed: big strips first
  const int istrip = sx * 64 + w * 16;             // this wave's 16 q-rows
  const int fr = l & 15, fkq = (l >> 4) * 8;
  const float scale = 0.125f;
  char* Pw = PtB[w];
  const int njt = sx + 1;                          // uniform across the block's 4 waves

  // Q fragments in registers for the whole loop
  short8 aqw0, aqw1, aqr0, aqr1;
  {
    unsigned qb = ((unsigned)bh * T_LEN + istrip + fr) * 64 + fkq;
    aqw0 = *(const short8*)(qrw + qb);
    aqw1 = *(const short8*)(qrw + qb + 32);
    aqr0 = *(const short8*)(qrr + qb);
    aqr1 = *(const short8*)(qrr + qb + 32);
  }

  // staging geometry: wave w stages K rows [16w..16w+15] and V d-rows [16w..16w+15]
  const int srow = 16 * w + (l >> 3);                          // +8 for second load
  const unsigned sswz = (unsigned)(((l & 7) ^ (l >> 3)) << 4); // write-side swizzle (bytes)
  const unsigned kgcol = (unsigned)(l & 7) * 8;                // global col (elems)
  const unsigned swzr = (unsigned)(fr & 7) << 4;               // read-side swizzle (bytes)

  const unsigned rbase = ((unsigned)h * 1152 + 64 + 1008 - istrip + fr) * 64 + fkq;

  float s_run[4] = {0.f, 0.f, 0.f, 0.f};
  f32x4 o[4] = {};                                 // [d-group][q]

  short8 sg0, sg1, sg2, sg3;                       // staged K(2) + V(2) in-flight regs
#define STAGE_LOAD(J0)                                                              \
  do {                                                                              \
    sg0 = *(const short8*)(kb + ((unsigned)bh * 1024 + (unsigned)(J0) + srow) * 64 + kgcol);      \
    sg1 = *(const short8*)(kb + ((unsigned)bh * 1024 + (unsigned)(J0) + srow + 8) * 64 + kgcol);  \
    sg2 = *(const short8*)(vt + ((unsigned)bh * 64 + srow) * 1024 + (unsigned)(J0) + kgcol);      \
    sg3 = *(const short8*)(vt + ((unsigned)bh * 64 + srow + 8) * 1024 + (unsigned)(J0) + kgcol);  \
  } while (0)
#define STAGE_WRITE(BUF)                                                            \
  do {                                                                              \
    char* KS_ = (char*)KV[BUF];                                                     \
    *(short8*)(KS_ + (unsigned)srow * 128 + sswz) = sg0;                            \
    *(short8*)(KS_ + (unsigned)(srow + 8) * 128 + sswz) = sg1;                      \
    *(short8*)(KS_ + 8192 + (unsigned)srow * 128 + sswz) = sg2;                     \
    *(short8*)(KS_ + 8192 + (unsigned)(srow + 8) * 128 + sswz) = sg3;               \
  } while (0)

  // prologue: stage tile 0
  STAGE_LOAD(0);
  STAGE_WRITE(0);
  __syncthreads();

  for (int jt = 0; jt < njt; ++jt) {
    const int j0 = jt << 6;
    const char* KS = (const char*)KV[jt & 1];

    // ---- issue next tile's stage loads early (latency hides under this tile) ----
    if (jt + 1 < njt) STAGE_LOAD((jt + 1) << 6);

    // ---- R loads (global -> regs, per-wave band) ----
    short8 rf[10];
    {
      unsigned roff = rbase + (unsigned)j0 * 64;
#pragma unroll
      for (int f = 0; f < 5; ++f) {
        rf[2 * f] = *(const short8*)(rhp + roff + f * 1024);
        rf[2 * f + 1] = *(const short8*)(rhp + roff + f * 1024 + 32);
      }
    }

    // ---- K from LDS (swizzled), AC / BD MFMA ----
    f32x4 ac[4] = {};
    f32x4 pb[5] = {};
    {
      short8 kf[8];
#pragma unroll
      for (int f = 0; f < 4; ++f) {
        unsigned rowb = (unsigned)(f * 16 + fr) * 128;
        kf[2 * f] = *(const short8*)(KS + rowb + (((unsigned)fkq * 2) ^ swzr));
        kf[2 * f + 1] = *(const short8*)(KS + rowb + (((unsigned)fkq * 2 + 64) ^ swzr));
      }
      __builtin_amdgcn_s_setprio(1);
#pragma unroll
      for (int f = 0; f < 4; ++f) {
        ac[f] = MFMA_BF16(aqw0, kf[2 * f], ac[f]);
        ac[f] = MFMA_BF16(aqw1, kf[2 * f + 1], ac[f]);
      }
#pragma unroll
      for (int f = 0; f < 5; ++f) {
        pb[f] = MFMA_BF16(aqr0, rf[2 * f], pb[f]);
        pb[f] = MFMA_BF16(aqr1, rf[2 * f + 1], pb[f]);
      }
      __builtin_amdgcn_s_setprio(0);
    }

    // ---- V from LDS (swizzled) -- issue before softmax so lgkm overlaps ----
    short8 vf[8];
#pragma unroll
    for (int dg = 0; dg < 4; ++dg) {
      unsigned rowb = 8192 + (unsigned)(dg * 16 + fr) * 128;
      vf[2 * dg] = *(const short8*)(KS + rowb + (((unsigned)fkq * 2) ^ swzr));
      vf[2 * dg + 1] = *(const short8*)(KS + rowb + (((unsigned)(64 + fkq * 2)) ^ swzr));
    }

    // ---- rel-shift gather + static-max softmax: P straight to LDS ----
#pragma unroll
    for (int q = 0; q < 4; ++q) {
      int ri = 4 * (l >> 4) + q;
      int e = 15 + fr - ri;                   // in [0,30]
      int src = (l & 48) | (e & 15);
      float sh[5];
#pragma unroll
      for (int f = 0; f < 5; ++f) sh[f] = __shfl(pb[f][q], src, 64);
      int hi = e >> 4;
      int ig = istrip + ri;
#pragma unroll
      for (int ni = 0; ni < 4; ++ni) {
        float pv = hi ? sh[ni + 1] : sh[ni];
        float s = (ac[ni][q] + pv) * scale - 20.0f;
        int jg = j0 + ni * 16 + fr;
        float p = (jg > ig) ? 0.f : __expf(s);
        *(ushort_t*)(Pw + (((ri * 128) + (ni * 16 + fr) * 2) ^ ((ri & 7) << 4))) = f2bf(p);
        s_run[q] += p;
      }
    }

    // ---- PV ----
    {
      short8 pa0 = *(const short8*)(Pw + ((fr * 128 + fkq * 2) ^ ((fr & 7) << 4)));
      short8 pa1 = *(const short8*)(Pw + ((fr * 128 + 64 + fkq * 2) ^ ((fr & 7) << 4)));
      __builtin_amdgcn_s_setprio(1);
#pragma unroll
      for (int dg = 0; dg < 4; ++dg) {
        o[dg] = MFMA_BF16(pa0, vf[2 * dg], o[dg]);
        o[dg] = MFMA_BF16(pa1, vf[2 * dg + 1], o[dg]);
      }
      __builtin_amdgcn_s_setprio(0);
    }

    // ---- write staged regs into the other buffer, then sync ----
    if (jt + 1 < njt) STAGE_WRITE((jt + 1) & 1);
    __syncthreads();
  }

  // ---- epilogue: one-time row-sum reduce, normalize, write ctx [T][B][E] bf16 ----
#pragma unroll
  for (int q = 0; q < 4; ++q) {
    float sq = s_run[q];
#pragma unroll
    for (int o2 = 8; o2; o2 >>= 1) sq += __shfl_xor(sq, o2, 64);
    s_run[q] = sq;
  }
#pragma unroll
  for (int dg = 0; dg < 4; ++dg) {
#pragma unroll
    for (int q = 0; q < 4; ++q) {
      int ig = istrip + 4 * (l >> 4) + q;
      int dd = dg * 16 + fr;
      float val = o[dg][q] / s_run[q];
      ctx[((size_t)ig * BATCH + b) * EMB + h * 64 + dd] = f2bf(val);
    }
  }
}

// ---------------- launch ----------------
extern "C" void kernel_launch(void* const* d_in, const int* in_sizes, int n_in,
                              void* d_out, int out_size, void* d_ws, size_t ws_size,
                              hipStream_t stream) {
  (void)in_sizes; (void)n_in; (void)out_size; (void)ws_size;
  const float* x = (const float*)d_in[0];
  const float* pos = (const float*)d_in[1];
  const float* in_w_mu = (const float*)d_in[3];
  const float* in_w_rho = (const float*)d_in[4];
  const float* in_w_eps = (const float*)d_in[5];
  const float* in_b_mu = (const float*)d_in[6];
  const float* in_b_rho = (const float*)d_in[7];
  const float* in_b_eps = (const float*)d_in[8];
  const float* pos_w_mu = (const float*)d_in[9];
  const float* pos_w_rho = (const float*)d_in[10];
  const float* pos_w_eps = (const float*)d_in[11];
  const float* pos_b_mu = (const float*)d_in[12];
  const float* pos_b_rho = (const float*)d_in[13];
  const float* pos_b_eps = (const float*)d_in[14];
  const float* out_w_mu = (const float*)d_in[15];
  const float* out_w_rho = (const float*)d_in[16];
  const float* out_w_eps = (const float*)d_in[17];
  const float* out_b_mu = (const float*)d_in[18];
  const float* out_b_rho = (const float*)d_in[19];
  const float* out_b_eps = (const float*)d_in[20];
  const float* rw_mu = (const float*)d_in[21];
  const float* rw_rho = (const float*)d_in[22];
  const float* rw_eps = (const float*)d_in[23];
  const float* rr_mu = (const float*)d_in[24];
  const float* rr_rho = (const float*)d_in[25];
  const float* rr_eps = (const float*)d_in[26];

  char* ws = (char*)d_ws;
  ushort_t* in_w_bf  = (ushort_t*)(ws + 0);          // 3072x1024 bf16
  ushort_t* pos_w_bf = (ushort_t*)(ws + 6291456);    // 1024x1024 bf16
  ushort_t* out_w_bf = (ushort_t*)(ws + 8388608);    // 1024x1024 bf16
  float* in_b  = (float*)(ws + 10485760);            // 3072
  float* pos_b = (float*)(ws + 10498048);            // 1024
  float* out_b = (float*)(ws + 10502144);            // 1024
  float* rwb   = (float*)(ws + 10506240);            // 1024
  float* rrb   = (float*)(ws + 10510336);            // 1024
  ushort_t* x_bf    = (ushort_t*)(ws + 10514432);    // 4096x1024 bf16
  ushort_t* posx_bf = (ushort_t*)(ws + 18903040);    // 1024x1024 bf16
  ushort_t* qrw = (ushort_t*)(ws + 21000192);        // [B][H][T][64] bf16
  ushort_t* qrr = (ushort_t*)(ws + 29388800);
  ushort_t* kb  = (ushort_t*)(ws + 37777408);
  ushort_t* vt  = (ushort_t*)(ws + 46166016);        // [B][H][64][T] bf16
  ushort_t* rhp = (ushort_t*)(ws + 54554624);        // [H][1152][64] bf16
  ushort_t* ctx = (ushort_t*)(ws + 56913920);        // [T][B][E] bf16

  sample_bf16x4_kernel<<<3072, 256, 0, stream>>>(in_w_mu, in_w_rho, in_w_eps, in_w_bf, 786432);
  sample_bf16x4_kernel<<<1024, 256, 0, stream>>>(pos_w_mu, pos_w_rho, pos_w_eps, pos_w_bf, 262144);
  sample_bf16x4_kernel<<<1024, 256, 0, stream>>>(out_w_mu, out_w_rho, out_w_eps, out_w_bf, 262144);
  sample_bias_kernel<<<28, 256, 0, stream>>>(in_b_mu, in_b_rho, in_b_eps, in_b,
                                             pos_b_mu, pos_b_rho, pos_b_eps, pos_b,
                                             out_b_mu, out_b_rho, out_b_eps, out_b,
                                             rw_mu, rw_rho, rw_eps, rwb,
                                             rr_mu, rr_rho, rr_eps, rrb);
  cast_bf16x4_kernel<<<4096, 256, 0, stream>>>(x, x_bf, 1048576);
  cast_bf16x4_kernel<<<1024, 256, 0, stream>>>(pos, posx_bf, 262144);
  zero_rhp_pad_kernel<<<512, 256, 0, stream>>>(rhp);

  gemm_qkv_fused_kernel<<<dim3(32, 24), 256, 0, stream>>>(x_bf, in_w_bf, in_b, rwb, rrb,
                                                          qrw, qrr, kb, vt);
  gemm_pos_fused_kernel<<<dim3(8, 8), 256, 0, stream>>>(posx_bf, pos_w_bf, pos_b, rhp);

  attn_kernel<<<dim3(1024), 256, 0, stream>>>(qrw, qrr, kb, vt, rhp, ctx);

  gemm_bt_kernel<<<dim3(32, 8), 256, 0, stream>>>(ctx, out_w_bf, out_b, (float*)d_out, 4096, 1024, 1024);
}

// Round 14
// 202.422 us; speedup vs baseline: 1.2520x; 1.1060x over previous
//
#include <hip/hip_runtime.h>

typedef unsigned short ushort_t;
typedef __attribute__((ext_vector_type(8))) short short8;
typedef __attribute__((ext_vector_type(4))) float f32x4;
typedef __attribute__((ext_vector_type(4))) unsigned short ush4;

#define MFMA_BF16(a, b, c) __builtin_amdgcn_mfma_f32_16x16x32_bf16((a), (b), (c), 0, 0, 0)

// async global->LDS, 16B/lane; LDS dest is wave-uniform base + lane*16 (linear layout required)
#define GLOAD_LDS16(GP, LP)                                                       \
  __builtin_amdgcn_global_load_lds(                                               \
      (const __attribute__((address_space(1))) void*)(GP),                        \
      (__attribute__((address_space(3))) void*)(LP), 16, 0, 0)

#define T_LEN 1024
#define BATCH 4
#define NHEAD 16
#define DHEAD 64
#define EMB 1024

__device__ __forceinline__ ushort_t f2bf(float f) {
  unsigned u = __float_as_uint(f);
  u += 0x7fffu + ((u >> 16) & 1u);
  return (ushort_t)(u >> 16);
}

// ---------------- elementwise ----------------
// all three weight matrices in one dispatch (vec4); boundaries are block-aligned
__global__ void sample_w_kernel(const float* __restrict__ im, const float* __restrict__ ir,
                                const float* __restrict__ ie, ushort_t* __restrict__ io,
                                const float* __restrict__ pm, const float* __restrict__ pr,
                                const float* __restrict__ pe, ushort_t* __restrict__ po,
                                const float* __restrict__ om, const float* __restrict__ orh,
                                const float* __restrict__ oe, ushort_t* __restrict__ oo) {
  int i = blockIdx.x * 256 + threadIdx.x;          // vec4 index, 1310720 total
  const float *mu, *rho, *eps;
  ushort_t* out;
  int j;
  if (i < 786432) { mu = im; rho = ir; eps = ie; out = io; j = i; }
  else if (i < 1048576) { mu = pm; rho = pr; eps = pe; out = po; j = i - 786432; }
  else { mu = om; rho = orh; eps = oe; out = oo; j = i - 1048576; }
  f32x4 m = *(const f32x4*)(mu + (size_t)j * 4);
  f32x4 r = *(const f32x4*)(rho + (size_t)j * 4);
  f32x4 e = *(const f32x4*)(eps + (size_t)j * 4);
  ush4 o;
#pragma unroll
  for (int k = 0; k < 4; ++k) o[k] = f2bf(m[k] + log1pf(__expf(r[k])) * e[k]);
  *(ush4*)(out + (size_t)j * 4) = o;
}

// all five bias vectors in one launch: 3072 + 4*1024 = 7168 threads
__global__ void sample_bias_kernel(
    const float* __restrict__ am, const float* __restrict__ ar, const float* __restrict__ ae, float* __restrict__ ao,
    const float* __restrict__ bm, const float* __restrict__ br, const float* __restrict__ be, float* __restrict__ bo,
    const float* __restrict__ cm, const float* __restrict__ cr, const float* __restrict__ ce, float* __restrict__ co,
    const float* __restrict__ dm, const float* __restrict__ dr, const float* __restrict__ de, float* __restrict__ dof,
    const float* __restrict__ em, const float* __restrict__ er, const float* __restrict__ ee, float* __restrict__ eo) {
  int i = blockIdx.x * 256 + threadIdx.x;
  if (i < 3072) {
    ao[i] = am[i] + log1pf(__expf(ar[i])) * ae[i];
  } else if (i < 4096) {
    int j = i - 3072; bo[j] = bm[j] + log1pf(__expf(br[j])) * be[j];
  } else if (i < 5120) {
    int j = i - 4096; co[j] = cm[j] + log1pf(__expf(cr[j])) * ce[j];
  } else if (i < 6144) {
    int j = i - 5120; dof[j] = dm[j] + log1pf(__expf(dr[j])) * de[j];
  } else if (i < 7168) {
    int j = i - 6144; eo[j] = em[j] + log1pf(__expf(er[j])) * ee[j];
  }
}

__global__ void cast_bf16x4_kernel(const float* __restrict__ in, ushort_t* __restrict__ out, int n4) {
  int i = blockIdx.x * 256 + threadIdx.x;
  if (i < n4) {
    f32x4 v = *(const f32x4*)(in + (size_t)i * 4);
    ush4 o;
#pragma unroll
    for (int j = 0; j < 4; ++j) o[j] = f2bf(v[j]);
    *(ush4*)(out + (size_t)i * 4) = o;
  }
}

// zero the rhp pad rows (phys rows 0..63 and 1088..1151 per head)
__global__ void zero_rhp_pad_kernel(ushort_t* __restrict__ rhp) {
  int idx = blockIdx.x * 256 + threadIdx.x;   // 16*128*64 = 131072
  int dd = idx & 63;
  int pr = (idx >> 6) & 127;
  int h = idx >> 13;
  int phys = (pr < 64) ? pr : (pr - 64 + 1088);
  rhp[((size_t)h * 1152 + phys) * 64 + dd] = 0;
}

// ---------------- GEMM (out-proj): C = A * Bt^T + bias, f32 out ----------------
__global__ __launch_bounds__(256, 2)
void gemm_bt_kernel(const ushort_t* __restrict__ A, const ushort_t* __restrict__ Bt,
                    const float* __restrict__ bias, float* __restrict__ C,
                    int M, int N, int K) {
  __shared__ ushort_t As[128 * 32];
  __shared__ ushort_t Bs[128 * 32];
  const int tid = threadIdx.x;
  const int w = tid >> 6, l = tid & 63;
  const int m0 = blockIdx.x * 128, n0 = blockIdx.y * 128;
  const int wr = w >> 1, wc = w & 1;
  const int fr = l & 15, fk = (l >> 4) * 8;

  f32x4 acc[4][4] = {};

  for (int k0 = 0; k0 < K; k0 += 32) {
    __syncthreads();
#pragma unroll
    for (int p = 0; p < 2; ++p) {
      int c = p * 256 + tid;
      int row = c >> 2, col = (c & 3) * 8;
      GLOAD_LDS16(&A[(size_t)(m0 + row) * K + k0 + col], &As[c * 8]);
      GLOAD_LDS16(&Bt[(size_t)(n0 + row) * K + k0 + col], &Bs[c * 8]);
    }
    __syncthreads();
    short8 af[4], bf[4];
#pragma unroll
    for (int mi = 0; mi < 4; ++mi) af[mi] = *(const short8*)(&As[(wr * 64 + mi * 16 + fr) * 32 + fk]);
#pragma unroll
    for (int ni = 0; ni < 4; ++ni) bf[ni] = *(const short8*)(&Bs[(wc * 64 + ni * 16 + fr) * 32 + fk]);
#pragma unroll
    for (int mi = 0; mi < 4; ++mi)
#pragma unroll
      for (int ni = 0; ni < 4; ++ni)
        acc[mi][ni] = MFMA_BF16(af[mi], bf[ni], acc[mi][ni]);
  }

#pragma unroll
  for (int ni = 0; ni < 4; ++ni) {
    int col = n0 + wc * 64 + ni * 16 + fr;
    float bv = bias[col];
#pragma unroll
    for (int mi = 0; mi < 4; ++mi) {
#pragma unroll
      for (int q = 0; q < 4; ++q) {
        int row = m0 + wr * 64 + mi * 16 + (l >> 4) * 4 + q;
        C[(size_t)row * N + col] = acc[mi][ni][q] + bv;
      }
    }
  }
}

// ---------------- merged QKV + pos GEMM: one dispatch, 832 blocks ----------------
// bid<768: qkv path (M=4096,N=3072, scatter epilogue); bid>=768: pos path (rhp epilogue).
__global__ __launch_bounds__(256, 2)
void gemm_qkvpos_kernel(const ushort_t* __restrict__ x_bf, const ushort_t* __restrict__ in_w_bf,
                        const float* __restrict__ in_b,
                        const float* __restrict__ rwb, const float* __restrict__ rrb,
                        const ushort_t* __restrict__ posx_bf, const ushort_t* __restrict__ pos_w_bf,
                        const float* __restrict__ pos_b,
                        ushort_t* __restrict__ qrw, ushort_t* __restrict__ qrr,
                        ushort_t* __restrict__ kbuf, ushort_t* __restrict__ vt,
                        ushort_t* __restrict__ rhp) {
  __shared__ ushort_t As[128 * 32];
  __shared__ ushort_t Bs[128 * 32];
  const int K = 1024;
  const int tid = threadIdx.x;
  const int w = tid >> 6, l = tid & 63;
  const int bid = blockIdx.x;
  const bool isPos = bid >= 768;
  int m0, n0;
  const ushort_t *A, *Bt;
  if (!isPos) {
    m0 = (bid & 31) * 128; n0 = (bid >> 5) * 128; A = x_bf; Bt = in_w_bf;
  } else {
    int pb2 = bid - 768;
    m0 = (pb2 & 7) * 128; n0 = (pb2 >> 3) * 128; A = posx_bf; Bt = pos_w_bf;
  }
  const int wr = w >> 1, wc = w & 1;
  const int fr = l & 15, fk = (l >> 4) * 8;

  f32x4 acc[4][4] = {};

  for (int k0 = 0; k0 < K; k0 += 32) {
    __syncthreads();
#pragma unroll
    for (int p = 0; p < 2; ++p) {
      int c = p * 256 + tid;
      int row = c >> 2, col = (c & 3) * 8;
      GLOAD_LDS16(&A[(size_t)(m0 + row) * K + k0 + col], &As[c * 8]);
      GLOAD_LDS16(&Bt[(size_t)(n0 + row) * K + k0 + col], &Bs[c * 8]);
    }
    __syncthreads();
    short8 af[4], bf[4];
#pragma unroll
    for (int mi = 0; mi < 4; ++mi) af[mi] = *(const short8*)(&As[(wr * 64 + mi * 16 + fr) * 32 + fk]);
#pragma unroll
    for (int ni = 0; ni < 4; ++ni) bf[ni] = *(const short8*)(&Bs[(wc * 64 + ni * 16 + fr) * 32 + fk]);
#pragma unroll
    for (int mi = 0; mi < 4; ++mi)
#pragma unroll
      for (int ni = 0; ni < 4; ++ni)
        acc[mi][ni] = MFMA_BF16(af[mi], bf[ni], acc[mi][ni]);
  }

  if (!isPos) {
#pragma unroll
    for (int ni = 0; ni < 4; ++ni) {
      int col = n0 + wc * 64 + ni * 16 + fr;
      int part = col >> 10;
      int e = col & 1023;
      int hh = e >> 6, dd = e & 63;
      float bv = in_b[col];
      float rwv = rwb[e];
      float rrv = rrb[e];
#pragma unroll
      for (int mi = 0; mi < 4; ++mi) {
#pragma unroll
        for (int q = 0; q < 4; ++q) {
          int row = m0 + wr * 64 + mi * 16 + (l >> 4) * 4 + q;
          int t = row >> 2, b = row & 3;
          float v = acc[mi][ni][q] + bv;
          if (part == 0) {
            unsigned idx = (((unsigned)(b * 16 + hh) * 1024 + t) << 6) + dd;
            qrw[idx] = f2bf(v + rwv);
            qrr[idx] = f2bf(v + rrv);
          } else if (part == 1) {
            unsigned idx = (((unsigned)(b * 16 + hh) * 1024 + t) << 6) + dd;
            kbuf[idx] = f2bf(v);
          } else {
            vt[(((unsigned)(b * 16 + hh) * 64 + dd) << 10) + t] = f2bf(v);
          }
        }
      }
    }
  } else {
#pragma unroll
    for (int ni = 0; ni < 4; ++ni) {
      int col = n0 + wc * 64 + ni * 16 + fr;
      int hh = col >> 6, dd = col & 63;
      float bv = pos_b[col];
#pragma unroll
      for (int mi = 0; mi < 4; ++mi) {
#pragma unroll
        for (int q = 0; q < 4; ++q) {
          int t = m0 + wr * 64 + mi * 16 + (l >> 4) * 4 + q;
          rhp[((unsigned)hh * 1152 + 64 + t) * 64 + dd] = f2bf(acc[mi][ni][q] + bv);
        }
      }
    }
  }
}

// ---------------- fused rel-shift attention v7: paired strips over shared staged K/V ----------
// Block handles strips sxA=15-p and sxB=p for one bh: stage K/V tile once, compute strip A
// always, strip B while jt<=p. Every block = exactly 17 work-units (uniform, no tail);
// barriers/staging 8704->6400; K/V global reads halved; 512 blocks = 2/CU all-resident.
// kf/vf reloaded from LDS per strip (transient regs -> no R9-style spill).
__global__ __launch_bounds__(256, 2)
void attn_kernel(const ushort_t* __restrict__ qrw, const ushort_t* __restrict__ qrr,
                 const ushort_t* __restrict__ kb, const ushort_t* __restrict__ vt,
                 const ushort_t* __restrict__ rhp, ushort_t* __restrict__ ctx) {
  __shared__ __attribute__((aligned(16))) ushort_t KV[2][8192];  // [buf][K 8KB | V 8KB]
  __shared__ __attribute__((aligned(16))) char PtB[4][2048];     // per-wave P transpose

  const int tid = threadIdx.x, w = tid >> 6, l = tid & 63;
  const int bid = blockIdx.x;
  const int g = bid & 63;
  const int h = ((g & 7) << 1) | ((g >> 3) & 1);   // bid%8 fixes the head-pair (XCD L2 locality)
  const int b = g >> 4;
  const int bh = b * 16 + h;
  const int p = bid >> 6;                          // pair index 0..7
  const int istA = (15 - p) * 64 + w * 16;         // strip A rows (big)
  const int istB = p * 64 + w * 16;                // strip B rows (small)
  const int njt = 16 - p;                          // staged tiles (strip A bound)
  const int njtB = p + 1;                          // strip B active tiles
  const int fr = l & 15, fkq = (l >> 4) * 8;
  const float scale = 0.125f;
  char* Pw = PtB[w];

  // Q fragments for both strips
  short8 aqwA0, aqwA1, aqrA0, aqrA1, aqwB0, aqwB1, aqrB0, aqrB1;
  {
    unsigned qa = ((unsigned)bh * T_LEN + istA + fr) * 64 + fkq;
    aqwA0 = *(const short8*)(qrw + qa);
    aqwA1 = *(const short8*)(qrw + qa + 32);
    aqrA0 = *(const short8*)(qrr + qa);
    aqrA1 = *(const short8*)(qrr + qa + 32);
    unsigned qb = ((unsigned)bh * T_LEN + istB + fr) * 64 + fkq;
    aqwB0 = *(const short8*)(qrw + qb);
    aqwB1 = *(const short8*)(qrw + qb + 32);
    aqrB0 = *(const short8*)(qrr + qb);
    aqrB1 = *(const short8*)(qrr + qb + 32);
  }

  // staging geometry: wave w stages K rows [16w..16w+15] and V d-rows [16w..16w+15]
  const int srow = 16 * w + (l >> 3);                          // +8 for second load
  const unsigned sswz = (unsigned)(((l & 7) ^ (l >> 3)) << 4); // write-side swizzle (bytes)
  const unsigned kgcol = (unsigned)(l & 7) * 8;                // global col (elems)
  const unsigned swzr = (unsigned)(fr & 7) << 4;               // read-side swizzle (bytes)

  const unsigned rbaseA = ((unsigned)h * 1152 + 64 + 1008 - istA + fr) * 64 + fkq;
  const unsigned rbaseB = ((unsigned)h * 1152 + 64 + 1008 - istB + fr) * 64 + fkq;

  float sA[4] = {0.f, 0.f, 0.f, 0.f}, sB[4] = {0.f, 0.f, 0.f, 0.f};
  f32x4 oA[4] = {}, oB[4] = {};

  short8 sg0, sg1, sg2, sg3;                       // staged K(2) + V(2) in-flight regs
#define STAGE_LOAD(J0)                                                              \
  do {                                                                              \
    sg0 = *(const short8*)(kb + ((unsigned)bh * 1024 + (unsigned)(J0) + srow) * 64 + kgcol);      \
    sg1 = *(const short8*)(kb + ((unsigned)bh * 1024 + (unsigned)(J0) + srow + 8) * 64 + kgcol);  \
    sg2 = *(const short8*)(vt + ((unsigned)bh * 64 + srow) * 1024 + (unsigned)(J0) + kgcol);      \
    sg3 = *(const short8*)(vt + ((unsigned)bh * 64 + srow + 8) * 1024 + (unsigned)(J0) + kgcol);  \
  } while (0)
#define STAGE_WRITE(BUF)                                                            \
  do {                                                                              \
    char* KS_ = (char*)KV[BUF];                                                     \
    *(short8*)(KS_ + (unsigned)srow * 128 + sswz) = sg0;                            \
    *(short8*)(KS_ + (unsigned)(srow + 8) * 128 + sswz) = sg1;                      \
    *(short8*)(KS_ + 8192 + (unsigned)srow * 128 + sswz) = sg2;                     \
    *(short8*)(KS_ + 8192 + (unsigned)(srow + 8) * 128 + sswz) = sg3;               \
  } while (0)

// full per-strip tile: R loads, K from LDS, AC/BD MFMA, rel-shift gather + static-max
// softmax (P -> Pw), V from LDS, PV. kf/vf transient inside (register-pressure discipline).
#define STRIP_TILE(AQW0, AQW1, AQR0, AQR1, RBASE, IST, SRUN, OACC)                   \
  do {                                                                               \
    short8 rf[10];                                                                   \
    unsigned roff = (RBASE) + (unsigned)j0 * 64;                                     \
    _Pragma("unroll")                                                                \
    for (int f = 0; f < 5; ++f) {                                                    \
      rf[2 * f] = *(const short8*)(rhp + roff + f * 1024);                           \
      rf[2 * f + 1] = *(const short8*)(rhp + roff + f * 1024 + 32);                  \
    }                                                                                \
    f32x4 ac[4] = {};                                                                \
    f32x4 pb[5] = {};                                                                \
    {                                                                                \
      short8 kf[8];                                                                  \
      _Pragma("unroll")                                                              \
      for (int f = 0; f < 4; ++f) {                                                  \
        unsigned rowb = (unsigned)(f * 16 + fr) * 128;                               \
        kf[2 * f] = *(const short8*)(KS + rowb + (((unsigned)fkq * 2) ^ swzr));      \
        kf[2 * f + 1] = *(const short8*)(KS + rowb + (((unsigned)fkq * 2 + 64) ^ swzr)); \
      }                                                                              \
      __builtin_amdgcn_s_setprio(1);                                                 \
      _Pragma("unroll")                                                              \
      for (int f = 0; f < 4; ++f) {                                                  \
        ac[f] = MFMA_BF16(AQW0, kf[2 * f], ac[f]);                                   \
        ac[f] = MFMA_BF16(AQW1, kf[2 * f + 1], ac[f]);                               \
      }                                                                              \
      _Pragma("unroll")                                                              \
      for (int f = 0; f < 5; ++f) {                                                  \
        pb[f] = MFMA_BF16(AQR0, rf[2 * f], pb[f]);                                   \
        pb[f] = MFMA_BF16(AQR1, rf[2 * f + 1], pb[f]);                               \
      }                                                                              \
      __builtin_amdgcn_s_setprio(0);                                                 \
    }                                                                                \
    _Pragma("unroll")                                                                \
    for (int q = 0; q < 4; ++q) {                                                    \
      int ri = 4 * (l >> 4) + q;                                                     \
      int e = 15 + fr - ri;                                                          \
      int src = (l & 48) | (e & 15);                                                 \
      float sh[5];                                                                   \
      _Pragma("unroll")                                                              \
      for (int f = 0; f < 5; ++f) sh[f] = __shfl(pb[f][q], src, 64);                 \
      int hi = e >> 4;                                                               \
      int ig = (IST) + ri;                                                           \
      _Pragma("unroll")                                                              \
      for (int ni = 0; ni < 4; ++ni) {                                               \
        float pv = hi ? sh[ni + 1] : sh[ni];                                         \
        float s = (ac[ni][q] + pv) * scale - 20.0f;                                  \
        int jg = j0 + ni * 16 + fr;                                                  \
        float pp = (jg > ig) ? 0.f : __expf(s);                                      \
        *(ushort_t*)(Pw + (((ri * 128) + (ni * 16 + fr) * 2) ^ ((ri & 7) << 4))) = f2bf(pp); \
        SRUN[q] += pp;                                                               \
      }                                                                              \
    }                                                                                \
    {                                                                                \
      short8 vf[8];                                                                  \
      _Pragma("unroll")                                                              \
      for (int dg = 0; dg < 4; ++dg) {                                               \
        unsigned rowb = 8192 + (unsigned)(dg * 16 + fr) * 128;                       \
        vf[2 * dg] = *(const short8*)(KS + rowb + (((unsigned)fkq * 2) ^ swzr));     \
        vf[2 * dg + 1] = *(const short8*)(KS + rowb + (((unsigned)(64 + fkq * 2)) ^ swzr)); \
      }                                                                              \
      short8 pa0 = *(const short8*)(Pw + ((fr * 128 + fkq * 2) ^ ((fr & 7) << 4)));  \
      short8 pa1 = *(const short8*)(Pw + ((fr * 128 + 64 + fkq * 2) ^ ((fr & 7) << 4))); \
      __builtin_amdgcn_s_setprio(1);                                                 \
      _Pragma("unroll")                                                              \
      for (int dg = 0; dg < 4; ++dg) {                                               \
        OACC[dg] = MFMA_BF16(pa0, vf[2 * dg], OACC[dg]);                             \
        OACC[dg] = MFMA_BF16(pa1, vf[2 * dg + 1], OACC[dg]);                         \
      }                                                                              \
      __builtin_amdgcn_s_setprio(0);                                                 \
    }                                                                                \
  } while (0)

  // prologue: stage tile 0
  STAGE_LOAD(0);
  STAGE_WRITE(0);
  __syncthreads();

  for (int jt = 0; jt < njt; ++jt) {
    const int j0 = jt << 6;
    const char* KS = (const char*)KV[jt & 1];

    // issue next tile's stage loads early (latency hides under this tile)
    if (jt + 1 < njt) STAGE_LOAD((jt + 1) << 6);

    STRIP_TILE(aqwA0, aqwA1, aqrA0, aqrA1, rbaseA, istA, sA, oA);
    if (jt < njtB) STRIP_TILE(aqwB0, aqwB1, aqrB0, aqrB1, rbaseB, istB, sB, oB);

    if (jt + 1 < njt) STAGE_WRITE((jt + 1) & 1);
    __syncthreads();
  }

  // ---- epilogue: row-sum reduce, normalize, write both strips ----
#pragma unroll
  for (int q = 0; q < 4; ++q) {
    float a = sA[q], bq = sB[q];
#pragma unroll
    for (int o2 = 8; o2; o2 >>= 1) {
      a += __shfl_xor(a, o2, 64);
      bq += __shfl_xor(bq, o2, 64);
    }
    sA[q] = a;
    sB[q] = bq;
  }
#pragma unroll
  for (int dg = 0; dg < 4; ++dg) {
#pragma unroll
    for (int q = 0; q < 4; ++q) {
      int dd = dg * 16 + fr;
      int igA = istA + 4 * (l >> 4) + q;
      ctx[((size_t)igA * BATCH + b) * EMB + h * 64 + dd] = f2bf(oA[dg][q] / sA[q]);
      int igB = istB + 4 * (l >> 4) + q;
      ctx[((size_t)igB * BATCH + b) * EMB + h * 64 + dd] = f2bf(oB[dg][q] / sB[q]);
    }
  }
}

// ---------------- launch ----------------
extern "C" void kernel_launch(void* const* d_in, const int* in_sizes, int n_in,
                              void* d_out, int out_size, void* d_ws, size_t ws_size,
                              hipStream_t stream) {
  (void)in_sizes; (void)n_in; (void)out_size; (void)ws_size;
  const float* x = (const float*)d_in[0];
  const float* pos = (const float*)d_in[1];
  const float* in_w_mu = (const float*)d_in[3];
  const float* in_w_rho = (const float*)d_in[4];
  const float* in_w_eps = (const float*)d_in[5];
  const float* in_b_mu = (const float*)d_in[6];
  const float* in_b_rho = (const float*)d_in[7];
  const float* in_b_eps = (const float*)d_in[8];
  const float* pos_w_mu = (const float*)d_in[9];
  const float* pos_w_rho = (const float*)d_in[10];
  const float* pos_w_eps = (const float*)d_in[11];
  const float* pos_b_mu = (const float*)d_in[12];
  const float* pos_b_rho = (const float*)d_in[13];
  const float* pos_b_eps = (const float*)d_in[14];
  const float* out_w_mu = (const float*)d_in[15];
  const float* out_w_rho = (const float*)d_in[16];
  const float* out_w_eps = (const float*)d_in[17];
  const float* out_b_mu = (const float*)d_in[18];
  const float* out_b_rho = (const float*)d_in[19];
  const float* out_b_eps = (const float*)d_in[20];
  const float* rw_mu = (const float*)d_in[21];
  const float* rw_rho = (const float*)d_in[22];
  const float* rw_eps = (const float*)d_in[23];
  const float* rr_mu = (const float*)d_in[24];
  const float* rr_rho = (const float*)d_in[25];
  const float* rr_eps = (const float*)d_in[26];

  char* ws = (char*)d_ws;
  ushort_t* in_w_bf  = (ushort_t*)(ws + 0);          // 3072x1024 bf16
  ushort_t* pos_w_bf = (ushort_t*)(ws + 6291456);    // 1024x1024 bf16
  ushort_t* out_w_bf = (ushort_t*)(ws + 8388608);    // 1024x1024 bf16
  float* in_b  = (float*)(ws + 10485760);            // 3072
  float* pos_b = (float*)(ws + 10498048);            // 1024
  float* out_b = (float*)(ws + 10502144);            // 1024
  float* rwb   = (float*)(ws + 10506240);            // 1024
  float* rrb   = (float*)(ws + 10510336);            // 1024
  ushort_t* x_bf    = (ushort_t*)(ws + 10514432);    // 4096x1024 bf16
  ushort_t* posx_bf = (ushort_t*)(ws + 18903040);    // 1024x1024 bf16
  ushort_t* qrw = (ushort_t*)(ws + 21000192);        // [B][H][T][64] bf16
  ushort_t* qrr = (ushort_t*)(ws + 29388800);
  ushort_t* kb  = (ushort_t*)(ws + 37777408);
  ushort_t* vt  = (ushort_t*)(ws + 46166016);        // [B][H][64][T] bf16
  ushort_t* rhp = (ushort_t*)(ws + 54554624);        // [H][1152][64] bf16
  ushort_t* ctx = (ushort_t*)(ws + 56913920);        // [T][B][E] bf16

  sample_w_kernel<<<5120, 256, 0, stream>>>(in_w_mu, in_w_rho, in_w_eps, in_w_bf,
                                            pos_w_mu, pos_w_rho, pos_w_eps, pos_w_bf,
                                            out_w_mu, out_w_rho, out_w_eps, out_w_bf);
  sample_bias_kernel<<<28, 256, 0, stream>>>(in_b_mu, in_b_rho, in_b_eps, in_b,
                                             pos_b_mu, pos_b_rho, pos_b_eps, pos_b,
                                             out_b_mu, out_b_rho, out_b_eps, out_b,
                                             rw_mu, rw_rho, rw_eps, rwb,
                                             rr_mu, rr_rho, rr_eps, rrb);
  cast_bf16x4_kernel<<<4096, 256, 0, stream>>>(x, x_bf, 1048576);
  cast_bf16x4_kernel<<<1024, 256, 0, stream>>>(pos, posx_bf, 262144);
  zero_rhp_pad_kernel<<<512, 256, 0, stream>>>(rhp);

  gemm_qkvpos_kernel<<<832, 256, 0, stream>>>(x_bf, in_w_bf, in_b, rwb, rrb,
                                              posx_bf, pos_w_bf, pos_b,
                                              qrw, qrr, kb, vt, rhp);

  attn_kernel<<<dim3(512), 256, 0, stream>>>(qrw, qrr, kb, vt, rhp, ctx);

  gemm_bt_kernel<<<dim3(32, 8), 256, 0, stream>>>(ctx, out_w_bf, out_b, (float*)d_out, 4096, 1024, 1024);
}